// Round 3
// baseline (98.856 us; speedup 1.0000x reference)
//
#include <hip/hip_runtime.h>

typedef long long i64;
typedef unsigned long long u64;

// ---------------------------------------------------------------------------
// Established facts (R1-R12):
//  - int64 inputs; int32 output [total*3] neg then [total] keep.
//  - Harness dur_us = fixed ~43 us fillBufferAligned (268 MB, untouchable)
//    + kernel. R4/R12 kernel ~53 us.
//  - R8 (broadcast tail search): NEUTRAL => not gather-BW bound at issue level.
//  - R10 (K=4 lockstep ILP): REGRESSED; time ~ 1/(resident waves). TLP, not
//    per-thread ILP, is the latency-hiding currency here.
//  - R12 (vector scan + 128-thr blocks): NEUTRAL (96.58 vs 96.85 harness).
//  - VALUBusy ~45%, occ ~71%, FETCH ~9.5 MB, WRITE 65.5 MB.
//  - Proven shell: ONE dispatch, width probe, no d_ws, no atomics, no
//    cross-lane intrinsics.
// R13 theory: probe latency is inflated by L2 thrash. The 8 MB table must
//  share per-XCD 4 MB L2 with 33.5 MB of streamed rand_vals reads and 65.5 MB
//  of streamed writes. Fix: non-temporal hints on ALL streaming accesses
//  (rand_vals loads, out_neg/out_keep stores) so table lines survive in L2;
//  restore 256-thr blocks with __launch_bounds__(256,8) occupancy hint
//  (VGPR=48 <= 64 so the bound is free).
// ---------------------------------------------------------------------------

template <typename T>
__device__ __forceinline__ bool interp_member(const T* __restrict__ table,
                                              int L, u64 key) {
    u64 v0 = (u64)table[0];
    u64 vN = (u64)table[L - 1];
    if (key <= v0) return key == v0;
    if (key >= vN) return key == vN;
    // invariant: table[lo] < key < table[hi]
    int lo = 0, hi = L - 1;
    u64 vlo = v0, vhi = vN;
    for (int it = 0; it < 12 && hi - lo > 8; ++it) {
        // f32 is plenty: rounding error ~ window * 6e-8 < 1 entry.
        float f = (float)(key - vlo) * __builtin_amdgcn_rcpf((float)(vhi - vlo));
        int mid = lo + (int)(f * (float)(hi - lo));
        if (mid <= lo) mid = lo + 1;           // clamp => strict shrink both ways
        if (mid >= hi) mid = hi - 1;
        u64 v = (u64)table[mid];
        if (v == key) return true;
        if (v < key) { lo = mid; vlo = v; }
        else         { hi = mid; vhi = v; }
    }
    while (hi - lo > 8) {                      // fallback; w.h.p. never runs
        int mid = lo + ((hi - lo) >> 1);
        u64 v = (u64)table[mid];
        if (v == key) return true;
        if (v < key) lo = mid; else hi = mid;
    }
    // Final scan of interior (lo, hi), <=7 entries.
    // i64 path: 4x 16B loads from aligned base m0.
    //  - m0 = (lo+1)&~1 in {lo, lo+1}; m0+7 >= lo+7 >= hi-1  => window covered.
    //  - clamp m0<=L-8 only fires when lo >= L-8; [L-8, L-1] still covers.
    //  - no false positives: table strictly sorted-unique and
    //    table[lo] < key < table[hi] => entries outside (lo,hi) != key.
    if constexpr (sizeof(T) == 8) {
        if (L >= 8) {
            int m0 = (lo + 1) & ~1;
            if (m0 > L - 8) m0 = L - 8;
            const ulonglong2* p = (const ulonglong2*)(table + m0);
            ulonglong2 a = p[0];
            ulonglong2 b = p[1];
            ulonglong2 c = p[2];
            ulonglong2 d = p[3];
            return (a.x == key) | (a.y == key) | (b.x == key) | (b.y == key) |
                   (c.x == key) | (c.y == key) | (d.x == key) | (d.y == key);
        }
    }
    bool eq = false;                           // int path / tiny-L: scalar scan
    for (int j = lo + 1; j < hi; ++j) eq |= ((u64)table[j] == key);
    return eq;
}

template <typename T>
__device__ __forceinline__ void sample_body(
    const T* __restrict__ pos, const T* __restrict__ rand_vals,
    const T* __restrict__ table,
    int* __restrict__ out_neg, int* __restrict__ out_keep,
    unsigned i, int split, int L, unsigned num_negs)
{
    unsigned b = i / num_negs;   // num_negs=64 -> shift
    i64 h = (i64)pos[3 * b + 0];
    i64 r = (i64)pos[3 * b + 1];
    i64 t = (i64)pos[3 * b + 2];
    // rand_vals: read exactly once, perfectly streamed -> keep out of L2
    i64 rv = (i64)__builtin_nontemporal_load(&rand_vals[i]);

    const bool corrupt_head = (i < (unsigned)split);
    i64 orig = corrupt_head ? h : t;
    // pad_idx==0 fast path: rng drawn in [1, NUM_ENTITIES); shift past original
    i64 repl = rv + (((rv >= orig) & (orig > 0)) ? 1 : 0);
    if (corrupt_head) h = repl; else t = repl;

    u64 key = ((u64)h << 42) | ((u64)r << 21) | (u64)t;

    // Store neg early (fire-and-forget); never re-read -> non-temporal so the
    // write stream does not evict table lines from L2.
    __builtin_nontemporal_store((int)h, &out_neg[3 * (size_t)i + 0]);
    __builtin_nontemporal_store((int)r, &out_neg[3 * (size_t)i + 1]);
    __builtin_nontemporal_store((int)t, &out_neg[3 * (size_t)i + 2]);

    bool in_set = interp_member(table, L, key);
    __builtin_nontemporal_store(in_set ? 0 : 1, &out_keep[i]);
}

__global__ __launch_bounds__(256, 8) void neg_sample_kernel(
    const void* __restrict__ pos, const void* __restrict__ rand_vals,
    const void* __restrict__ table,
    int* __restrict__ out_neg, int* __restrict__ out_keep,
    int total, int split, int L, unsigned num_negs)
{
    unsigned i = blockIdx.x * blockDim.x + threadIdx.x;
    if (i >= (unsigned)total) return;

    // Width probe (R2-proven): pos int32-view word 3 == 0 iff int64 storage.
    const int* pw = (const int*)pos;
    const bool is64 = (pw[3] == 0);   // wave-uniform, L1-hot

    if (is64) {
        sample_body<i64>((const i64*)pos, (const i64*)rand_vals, (const i64*)table,
                         out_neg, out_keep, i, split, L, num_negs);
    } else {
        sample_body<int>((const int*)pos, (const int*)rand_vals, (const int*)table,
                         out_neg, out_keep, i, split, L, num_negs);
    }
}

extern "C" void kernel_launch(void* const* d_in, const int* in_sizes, int n_in,
                              void* d_out, int out_size, void* d_ws, size_t ws_size,
                              hipStream_t stream) {
    const void* pos       = d_in[0];
    const void* rand_vals = d_in[1];
    const void* table     = d_in[2];

    const int B     = in_sizes[0] / 3;
    const int total = in_sizes[1];
    const int L     = in_sizes[2];
    const unsigned num_negs = (unsigned)(total / B);
    const int split = (total + 1) / 2;   // ceil(total/2)

    int* out_neg  = (int*)d_out;
    int* out_keep = out_neg + (size_t)total * 3;

    const int threads = 256;
    const int blocks  = (total + threads - 1) / threads;
    neg_sample_kernel<<<blocks, threads, 0, stream>>>(
        pos, rand_vals, table, out_neg, out_keep, total, split, L, num_negs);
}

// Round 5
// 96.113 us; speedup vs baseline: 1.0285x; 1.0285x over previous
//
#include <hip/hip_runtime.h>

typedef long long i64;
typedef unsigned long long u64;

// ---------------------------------------------------------------------------
// Established facts (R1-R14):
//  - int64 inputs; int32 output [total*3] neg then [total] keep.
//  - Harness dur_us = fixed ~43 us fillBufferAligned (268 MB, untouchable)
//    + kernel. R4/R12 kernel ~53 us.
//  - R8 (broadcast tail search): NEUTRAL => not gather-issue/BW bound at
//    current rates.
//  - R10 (K=4 lockstep ILP): REGRESSED; occupancy halved, VALU +70%.
//  - R12 (vector scan, 128-thr): NEUTRAL. R13 (non-temporal hints): NEUTRAL
//    to slightly negative => L2 stream-thrash not dominant. NT reverted.
//  - VALUBusy PINNED ~45-46% across R4/R10 => per-wave duty ~8%; per item
//    ~270 VALU-cy vs ~3100 stall-cy = ~4-5 dependent epochs x ~700-800 cy.
//    KERNEL IS EPOCH-LATENCY-BOUND: the lever is # dependent memory epochs.
//  - R14 (line-probe + readfirstlane scalarization): INFRA ABORT ("container
//    failed twice", no counters). Abort rounds historically unreliable, but
//    every abort correlated with shell deviations; R14 used readfirstlane,
//    violating the "no cross-lane intrinsics" shell rule.
//  - Proven shell: ONE dispatch, width probe, 256-thr blocks, no d_ws, no
//    atomics, no cross-lane intrinsics.
// R15: resubmit R14's LINE-PROBE search ONLY (readfirstlane path removed,
//  plain per-lane division restored -- it was ~10 VALU of ~270, not worth
//  the shell risk). Theory under test: epochs ~5 -> ~3.2.
//   After one scalar interp probe, every probe reads a full 64B-aligned line
//   (8 entries, 4x ulonglong2, same cache line -> one L2 fill). If the line
//   brackets the key (e0 <= key <= e7), membership is decided immediately
//   (sortedness => any equal entry must lie inside the line): kills the
//   separate final-scan epoch and terminates ~1.5 epochs earlier. L2
//   line-traffic per item DROPS (~4.7 -> ~3.2 lines).
// ---------------------------------------------------------------------------

// ---- i64 path: line-probe interpolation membership -------------------------
__device__ __forceinline__ bool member_i64(const i64* __restrict__ table,
                                           int L, u64 key) {
    if (L < 16) {                       // trivial guard (never in bench)
        bool eq = false;
        for (int j = 0; j < L; ++j) eq |= ((u64)table[j] == key);
        return eq;
    }
    u64 v0 = (u64)table[0];
    u64 vN = (u64)table[L - 1];
    if (key <= v0) return key == v0;
    if (key >= vN) return key == vN;
    // invariant: table[lo] < key < table[hi]
    int lo = 0, hi = L - 1;
    u64 vlo = v0, vhi = vN;

    // epoch 1: scalar interp probe (hit prob ~0 at window ~1M entries)
    {
        float f = (float)(key - vlo) * __builtin_amdgcn_rcpf((float)(vhi - vlo));
        int mid = lo + (int)(f * (float)(hi - lo));
        if (mid <= lo) mid = lo + 1;           // clamp => strict shrink
        if (mid >= hi) mid = hi - 1;
        u64 v = (u64)table[mid];
        if (v == key) return true;
        if (v < key) { lo = mid; vlo = v; }
        else         { hi = mid; vhi = v; }
        if (hi - lo <= 1) return false;
    }

    // epochs 2..: 64B line probes with value-bracket termination
    for (int it = 0; it < 8; ++it) {
        float f = (float)(key - vlo) * __builtin_amdgcn_rcpf((float)(vhi - vlo));
        int p = lo + (int)(f * (float)(hi - lo));
        int m = (p - 3) & ~7;               // 64B-aligned 8-entry block
        if (m < 0) m = 0;
        if (m > L - 8) m = L - 8;
        const ulonglong2* q = (const ulonglong2*)(table + m);  // 16B aligned
        ulonglong2 a = q[0], b = q[1], c = q[2], d = q[3];     // one line
        if (a.x <= key && d.y >= key) {
            // sorted: entries below m are < a.x <= key, entries above m+7
            // are > d.y >= key => any equal entry lies in [m, m+7]. Decide.
            return (a.x == key) | (a.y == key) | (b.x == key) | (b.y == key) |
                   (c.x == key) | (c.y == key) | (d.x == key) | (d.y == key);
        }
        if (d.y < key) {                    // whole line below key
            if (m + 7 > lo) { lo = m + 7; vlo = d.y; } else break;
        } else {                            // a.x > key: whole line above key
            if (m < hi)     { hi = m;     vhi = a.x; } else break;
        }
        if (hi - lo <= 1) return false;
    }

    // fallback (w.h.p. never runs): proven binary + 64B window scan
    while (hi - lo > 8) {
        int mid = lo + ((hi - lo) >> 1);
        u64 v = (u64)table[mid];
        if (v == key) return true;
        if (v < key) lo = mid; else hi = mid;
    }
    int m0 = (lo + 1) & ~1;
    if (m0 > L - 8) m0 = L - 8;
    if (m0 < 0) m0 = 0;
    const ulonglong2* q = (const ulonglong2*)(table + m0);
    ulonglong2 a = q[0], b = q[1], c = q[2], d = q[3];
    return (a.x == key) | (a.y == key) | (b.x == key) | (b.y == key) |
           (c.x == key) | (c.y == key) | (d.x == key) | (d.y == key);
}

// ---- generic (int32 table) path: proven R4 interp search -------------------
template <typename T>
__device__ __forceinline__ bool interp_member(const T* __restrict__ table,
                                              int L, u64 key) {
    if constexpr (sizeof(T) == 8) {
        return member_i64((const i64*)table, L, key);
    }
    u64 v0 = (u64)table[0];
    u64 vN = (u64)table[L - 1];
    if (key <= v0) return key == v0;
    if (key >= vN) return key == vN;
    int lo = 0, hi = L - 1;
    u64 vlo = v0, vhi = vN;
    for (int it = 0; it < 12 && hi - lo > 8; ++it) {
        float f = (float)(key - vlo) * __builtin_amdgcn_rcpf((float)(vhi - vlo));
        int mid = lo + (int)(f * (float)(hi - lo));
        if (mid <= lo) mid = lo + 1;
        if (mid >= hi) mid = hi - 1;
        u64 v = (u64)table[mid];
        if (v == key) return true;
        if (v < key) { lo = mid; vlo = v; }
        else         { hi = mid; vhi = v; }
    }
    while (hi - lo > 8) {
        int mid = lo + ((hi - lo) >> 1);
        u64 v = (u64)table[mid];
        if (v == key) return true;
        if (v < key) lo = mid; else hi = mid;
    }
    bool eq = false;
    for (int j = lo + 1; j < hi; ++j) eq |= ((u64)table[j] == key);
    return eq;
}

template <typename T>
__device__ __forceinline__ void sample_body(
    const T* __restrict__ pos, const T* __restrict__ rand_vals,
    const T* __restrict__ table,
    int* __restrict__ out_neg, int* __restrict__ out_keep,
    unsigned i, int split, int L, unsigned num_negs)
{
    unsigned b = i / num_negs;   // num_negs=64 -> compiler emits shift
    i64 h = (i64)pos[3 * (size_t)b + 0];
    i64 r = (i64)pos[3 * (size_t)b + 1];
    i64 t = (i64)pos[3 * (size_t)b + 2];
    i64 rv = (i64)rand_vals[i];

    const bool corrupt_head = (i < (unsigned)split);
    i64 orig = corrupt_head ? h : t;
    // pad_idx==0 fast path: rng drawn in [1, NUM_ENTITIES); shift past original
    i64 repl = rv + (((rv >= orig) & (orig > 0)) ? 1 : 0);
    if (corrupt_head) h = repl; else t = repl;

    u64 key = ((u64)h << 42) | ((u64)r << 21) | (u64)t;

    // Store neg early: fire-and-forget, frees values during the search.
    out_neg[3 * (size_t)i + 0] = (int)h;
    out_neg[3 * (size_t)i + 1] = (int)r;
    out_neg[3 * (size_t)i + 2] = (int)t;

    bool in_set = interp_member(table, L, key);
    out_keep[i] = in_set ? 0 : 1;
}

__global__ __launch_bounds__(256) void neg_sample_kernel(
    const void* __restrict__ pos, const void* __restrict__ rand_vals,
    const void* __restrict__ table,
    int* __restrict__ out_neg, int* __restrict__ out_keep,
    int total, int split, int L, unsigned num_negs)
{
    unsigned i = blockIdx.x * blockDim.x + threadIdx.x;
    if (i >= (unsigned)total) return;

    // Width probe (R2-proven): pos int32-view word 3 == 0 iff int64 storage.
    const int* pw = (const int*)pos;
    const bool is64 = (pw[3] == 0);   // wave-uniform, L1-hot

    if (is64) {
        sample_body<i64>((const i64*)pos, (const i64*)rand_vals, (const i64*)table,
                         out_neg, out_keep, i, split, L, num_negs);
    } else {
        sample_body<int>((const int*)pos, (const int*)rand_vals, (const int*)table,
                         out_neg, out_keep, i, split, L, num_negs);
    }
}

extern "C" void kernel_launch(void* const* d_in, const int* in_sizes, int n_in,
                              void* d_out, int out_size, void* d_ws, size_t ws_size,
                              hipStream_t stream) {
    const void* pos       = d_in[0];
    const void* rand_vals = d_in[1];
    const void* table     = d_in[2];

    const int B     = in_sizes[0] / 3;
    const int total = in_sizes[1];
    const int L     = in_sizes[2];
    const unsigned num_negs = (unsigned)(total / B);
    const int split = (total + 1) / 2;   // ceil(total/2)

    int* out_neg  = (int*)d_out;
    int* out_keep = out_neg + (size_t)total * 3;

    const int threads = 256;
    const int blocks  = (total + threads - 1) / threads;
    neg_sample_kernel<<<blocks, threads, 0, stream>>>(
        pos, rand_vals, table, out_neg, out_keep, total, split, L, num_negs);
}

// Round 6
// 95.404 us; speedup vs baseline: 1.0362x; 1.0074x over previous
//
#include <hip/hip_runtime.h>

typedef long long i64;
typedef unsigned long long u64;

// ---------------------------------------------------------------------------
// Established facts (R1-R15):
//  - int64 inputs; int32 output [total*3] neg then [total] keep.
//  - Harness dur_us = fixed ~43 us fillBufferAligned + kernel (~53 us stable).
//  - R8/R12/R13/R15 all NEUTRAL despite 30-70% swings in per-item loads and
//    line-touches => ample gather/L2/VALU throughput headroom; kernel is
//    bound by (serial epochs) x (latency) / (resident waves).
//  - R10 (K=4): REGRESSED via occupancy halving; TLP is the currency.
//  - R15 line-probe only cut expected epochs ~4.7 -> ~4.2 (interp error after
//    probe 1 is ~+-500 entries >> 8-entry line) -- neutral as predicted by
//    corrected math.
//  - R14 abort correlated with readfirstlane; shell rule reaffirmed: ONE
//    dispatch, width probe, 256-thr blocks, no d_ws, no atomics, no
//    cross-lane intrinsics.
// R16: BUY DEPTH WITH WIDTH (throughput is free, depth is the cost):
//  epoch 1 = 4 PARALLEL scalar probes at global-interp p + {-750,-250,250,750}
//            (covers ~1.8 sigma of the ~sqrt(L)/2 prediction error) ->
//            window <=500 w/ endpoint values, in ONE latency round-trip.
//  epoch 2+ = 16-entry (128B, 8x ulonglong2) contiguous block centered on
//            window-interp prediction; block brackets key -> membership
//            decided immediately (sorted); else narrow & repeat (~60%/~90%).
//  Expected serial epochs ~4.2 -> ~2.5. Loads/item ~8 -> ~14 (proven free).
//  VGPR ~65-75: keeps >=6 waves/SIMD cap (75%) >= achieved 71% occupancy.
//  Falsification: if neutral, epoch model is dead; declare fixed-cost bound.
// ---------------------------------------------------------------------------

// ---- i64 path: wide-probe interpolation membership -------------------------
__device__ __forceinline__ bool member_i64(const i64* __restrict__ table,
                                           int L, u64 key) {
    if (L < 48) {                       // trivial guard (never in bench)
        bool eq = false;
        for (int j = 0; j < L; ++j) eq |= ((u64)table[j] == key);
        return eq;
    }
    u64 v0 = (u64)table[0];
    u64 vN = (u64)table[L - 1];
    if (key <= v0) return key == v0;
    if (key >= vN) return key == vN;
    int lo = 0, hi = L - 1;             // invariant: table[lo] < key < table[hi]
    u64 vlo = v0, vhi = vN;

    // ---- epoch 1: 4 parallel probes around the global interp prediction ----
    {
        float f = (float)(key - v0) * __builtin_amdgcn_rcpf((float)(vN - v0));
        int p = (int)(f * (float)(L - 1));
        int m0 = p - 750, m1 = p - 250, m2 = p + 250, m3 = p + 750;
        m0 = m0 < 1 ? 1 : (m0 > L - 2 ? L - 2 : m0);
        m1 = m1 < 1 ? 1 : (m1 > L - 2 ? L - 2 : m1);
        m2 = m2 < 1 ? 1 : (m2 > L - 2 ? L - 2 : m2);
        m3 = m3 < 1 ? 1 : (m3 > L - 2 ? L - 2 : m3);
        // 4 independent loads -> one vmcnt wait (one latency epoch)
        u64 w0 = (u64)table[m0];
        u64 w1 = (u64)table[m1];
        u64 w2 = (u64)table[m2];
        u64 w3 = (u64)table[m3];
        if ((w0 == key) | (w1 == key) | (w2 == key) | (w3 == key)) return true;
        // tighten lo with ascending probes (last winner = tightest)
        if (w0 < key && m0 > lo) { lo = m0; vlo = w0; }
        if (w1 < key && m1 > lo) { lo = m1; vlo = w1; }
        if (w2 < key && m2 > lo) { lo = m2; vlo = w2; }
        if (w3 < key && m3 > lo) { lo = m3; vlo = w3; }
        // tighten hi with descending probes (last winner = tightest)
        if (w3 > key && m3 < hi) { hi = m3; vhi = w3; }
        if (w2 > key && m2 < hi) { hi = m2; vhi = w2; }
        if (w1 > key && m1 < hi) { hi = m1; vhi = w1; }
        if (w0 > key && m0 < hi) { hi = m0; vhi = w0; }
        if (hi - lo <= 1) return false;
    }

    // ---- epochs 2..: 16-entry (128B) block probes with bracket decision ----
    #pragma unroll 1
    for (int it = 0; it < 8; ++it) {
        float f = (float)(key - vlo) * __builtin_amdgcn_rcpf((float)(vhi - vlo));
        int q = lo + (int)(f * (float)(hi - lo));
        int m = (q - 8) & ~1;               // 16B-aligned block start
        if (m < 0) m = 0;
        if (m > L - 16) m = L - 16;
        const ulonglong2* qp = (const ulonglong2*)(table + m);
        ulonglong2 a0 = qp[0], a1 = qp[1], a2 = qp[2], a3 = qp[3];
        ulonglong2 a4 = qp[4], a5 = qp[5], a6 = qp[6], a7 = qp[7];
        u64 e0 = a0.x, e15 = a7.y;
        if (e0 <= key && e15 >= key) {
            // sorted: entries below m are < e0 <= key, above m+15 are > key
            // => any equal entry lies inside the block. Decide now.
            return (a0.x == key) | (a0.y == key) | (a1.x == key) | (a1.y == key) |
                   (a2.x == key) | (a2.y == key) | (a3.x == key) | (a3.y == key) |
                   (a4.x == key) | (a4.y == key) | (a5.x == key) | (a5.y == key) |
                   (a6.x == key) | (a6.y == key) | (a7.x == key) | (a7.y == key);
        }
        bool prog = false;
        if (e15 < key) {                    // whole block below key
            if (m + 15 > lo) { lo = m + 15; vlo = e15; prog = true; }
        } else {                            // e0 > key: whole block above key
            if (m < hi)      { hi = m;      vhi = e0;  prog = true; }
        }
        if (hi - lo <= 1) return false;
        if (!prog) break;                   // degenerate clamp -> fallback
    }

    // fallback (w.h.p. never runs): proven binary + 64B aligned window scan
    while (hi - lo > 8) {
        int mid = lo + ((hi - lo) >> 1);
        u64 v = (u64)table[mid];
        if (v == key) return true;
        if (v < key) lo = mid; else hi = mid;
    }
    int m0 = (lo + 1) & ~1;
    if (m0 > L - 8) m0 = L - 8;
    if (m0 < 0) m0 = 0;
    const ulonglong2* q2 = (const ulonglong2*)(table + m0);
    ulonglong2 a = q2[0], b = q2[1], c = q2[2], d = q2[3];
    return (a.x == key) | (a.y == key) | (b.x == key) | (b.y == key) |
           (c.x == key) | (c.y == key) | (d.x == key) | (d.y == key);
}

// ---- generic (int32 table) path: proven R4 interp search -------------------
template <typename T>
__device__ __forceinline__ bool interp_member(const T* __restrict__ table,
                                              int L, u64 key) {
    if constexpr (sizeof(T) == 8) {
        return member_i64((const i64*)table, L, key);
    }
    u64 v0 = (u64)table[0];
    u64 vN = (u64)table[L - 1];
    if (key <= v0) return key == v0;
    if (key >= vN) return key == vN;
    int lo = 0, hi = L - 1;
    u64 vlo = v0, vhi = vN;
    for (int it = 0; it < 12 && hi - lo > 8; ++it) {
        float f = (float)(key - vlo) * __builtin_amdgcn_rcpf((float)(vhi - vlo));
        int mid = lo + (int)(f * (float)(hi - lo));
        if (mid <= lo) mid = lo + 1;
        if (mid >= hi) mid = hi - 1;
        u64 v = (u64)table[mid];
        if (v == key) return true;
        if (v < key) { lo = mid; vlo = v; }
        else         { hi = mid; vhi = v; }
    }
    while (hi - lo > 8) {
        int mid = lo + ((hi - lo) >> 1);
        u64 v = (u64)table[mid];
        if (v == key) return true;
        if (v < key) lo = mid; else hi = mid;
    }
    bool eq = false;
    for (int j = lo + 1; j < hi; ++j) eq |= ((u64)table[j] == key);
    return eq;
}

template <typename T>
__device__ __forceinline__ void sample_body(
    const T* __restrict__ pos, const T* __restrict__ rand_vals,
    const T* __restrict__ table,
    int* __restrict__ out_neg, int* __restrict__ out_keep,
    unsigned i, int split, int L, unsigned num_negs)
{
    unsigned b = i / num_negs;   // num_negs=64 -> compiler emits shift
    i64 h = (i64)pos[3 * (size_t)b + 0];
    i64 r = (i64)pos[3 * (size_t)b + 1];
    i64 t = (i64)pos[3 * (size_t)b + 2];
    i64 rv = (i64)rand_vals[i];

    const bool corrupt_head = (i < (unsigned)split);
    i64 orig = corrupt_head ? h : t;
    // pad_idx==0 fast path: rng drawn in [1, NUM_ENTITIES); shift past original
    i64 repl = rv + (((rv >= orig) & (orig > 0)) ? 1 : 0);
    if (corrupt_head) h = repl; else t = repl;

    u64 key = ((u64)h << 42) | ((u64)r << 21) | (u64)t;

    // Store neg early: fire-and-forget, frees values during the search.
    out_neg[3 * (size_t)i + 0] = (int)h;
    out_neg[3 * (size_t)i + 1] = (int)r;
    out_neg[3 * (size_t)i + 2] = (int)t;

    bool in_set = interp_member(table, L, key);
    out_keep[i] = in_set ? 0 : 1;
}

__global__ __launch_bounds__(256) void neg_sample_kernel(
    const void* __restrict__ pos, const void* __restrict__ rand_vals,
    const void* __restrict__ table,
    int* __restrict__ out_neg, int* __restrict__ out_keep,
    int total, int split, int L, unsigned num_negs)
{
    unsigned i = blockIdx.x * blockDim.x + threadIdx.x;
    if (i >= (unsigned)total) return;

    // Width probe (R2-proven): pos int32-view word 3 == 0 iff int64 storage.
    const int* pw = (const int*)pos;
    const bool is64 = (pw[3] == 0);   // wave-uniform, L1-hot

    if (is64) {
        sample_body<i64>((const i64*)pos, (const i64*)rand_vals, (const i64*)table,
                         out_neg, out_keep, i, split, L, num_negs);
    } else {
        sample_body<int>((const int*)pos, (const int*)rand_vals, (const int*)table,
                         out_neg, out_keep, i, split, L, num_negs);
    }
}

extern "C" void kernel_launch(void* const* d_in, const int* in_sizes, int n_in,
                              void* d_out, int out_size, void* d_ws, size_t ws_size,
                              hipStream_t stream) {
    const void* pos       = d_in[0];
    const void* rand_vals = d_in[1];
    const void* table     = d_in[2];

    const int B     = in_sizes[0] / 3;
    const int total = in_sizes[1];
    const int L     = in_sizes[2];
    const unsigned num_negs = (unsigned)(total / B);
    const int split = (total + 1) / 2;   // ceil(total/2)

    int* out_neg  = (int*)d_out;
    int* out_keep = out_neg + (size_t)total * 3;

    const int threads = 256;
    const int blocks  = (total + threads - 1) / threads;
    neg_sample_kernel<<<blocks, threads, 0, stream>>>(
        pos, rand_vals, table, out_neg, out_keep, total, split, L, num_negs);
}